// Round 1
// 116.700 us; speedup vs baseline: 1.1639x; 1.1639x over previous
//
#include <hip/hip_runtime.h>

// MC3DAD kNN(k=5) covariance-trace curvature. B=8, N=4096, f32.
// Round 4: scan restructure.
//  (1) Q=2 queries per lane per candidate read -> ds_read_b128 traffic
//      halves (one candidate feeds 2 pairs).
//  (2) Keep-candidate recording moved from the LDS always-write buffer into
//      per-chunk register bitmasks (mask=(mask<<1)|keep is one v_addc).
//      All scan-side LDS writes eliminated; 64 KiB LDS freed. Drains
//      bit-reverse the mask and walk ctz -> ascending candidate-index order,
//      identical insertion semantics to round 3.
//  (3) Wave-shared threshold: after every drain the 8 segment-lanes of a
//      query shfl-min their partial 5th-best, so tau tracks the GLOBAL 5th
//      best seen so far (min over lanes of a subset-5th >= union-5th, so the
//      filter can never reject a true top-5 candidate; same 6e-5 fast-fma
//      margin as the proven kernel). Keep rate drops ~8x -> smaller drains.
//  Selection machinery is bit-identical to round 3 (absmax 0.0): exact
//  numpy-tree dd recompute, strict-< push5 in ascending index order, final
//  ranking by packed (sqrt-dist, idx) u64 keys, same epilogue arithmetic.

typedef unsigned long long ull;

constexpr int N_PTS  = 4096;
constexpr int BATCH  = 8;
constexpr int KNN    = 5;
constexpr int SEG    = 8;              // segment-lanes per query (lane>>3)
constexpr int SEGLEN = N_PTS / SEG;    // 512 candidates per lane
constexpr int NTHR   = 512;            // 8 waves, 128 queries per block
constexpr int QPW    = 16;             // queries per wave (2 octets of 8)
constexpr int QPB    = (NTHR / 64) * QPW;   // 128

__device__ __forceinline__ int swz(int j) { return j + (j >> 9); } // +16B/segment

__device__ __forceinline__ ull umin64(ull a, ull b) { return a < b ? a : b; }
__device__ __forceinline__ ull umax64(ull a, ull b) { return a < b ? b : a; }

// Branchless stable insert of (dd,idx) into ascending 5-list (strict <).
// Callers guarantee ascending-index insertion order, so equal-dd entries
// stay in index order (matches jax.lax.top_k stability).
__device__ __forceinline__ void push5(float dd, int idx,
                                      float d[KNN], int ix[KNN])
{
    float ad = dd; int ai = idx;
    #pragma unroll
    for (int p = 0; p < KNN - 1; ++p) {
        const bool lt = ad < d[p];
        const float md = lt ? ad : d[p];
        const int   mi = lt ? ai : ix[p];
        const float xd = lt ? d[p] : ad;
        const int   xi = lt ? ix[p] : ai;
        d[p] = md; ix[p] = mi; ad = xd; ai = xi;
    }
    const bool lt = ad < d[KNN - 1];
    d[KNN - 1]  = lt ? ad : d[KNN - 1];
    ix[KNN - 1] = lt ? ai : ix[KNN - 1];
}

// Merge two ascending sorted 5-lists (u64 lex keys) -> ascending top-5.
__device__ __forceinline__ void merge5(ull a[KNN], const ull b[KNN])
{
    const ull r0 = umin64(a[0], b[0]);
    const ull r1 = umin64(umin64(a[1], b[1]), umax64(a[0], b[0]));
    const ull r2 = umin64(umin64(a[2], b[2]),
                          umin64(umax64(a[1], b[0]), umax64(a[0], b[1])));
    const ull r3 = umin64(umin64(a[3], b[3]),
                   umin64(umax64(a[2], b[0]),
                   umin64(umax64(a[1], b[1]), umax64(a[0], b[2]))));
    const ull r4 = umin64(umin64(a[4], b[4]),
                   umin64(umin64(umax64(a[3], b[0]), umax64(a[2], b[1])),
                          umin64(umax64(a[1], b[2]), umax64(a[0], b[3]))));
    a[0] = r0; a[1] = r1; a[2] = r2; a[3] = r3; a[4] = r4;
}

__device__ __forceinline__ void sort5(ull key[KNN])
{
    #pragma unroll
    for (int i = 0; i < KNN - 1; ++i)
        #pragma unroll
        for (int p = 0; p < KNN - 1 - i; ++p) {
            const ull lo = umin64(key[p], key[p + 1]);
            const ull hi = umax64(key[p], key[p + 1]);
            key[p] = lo; key[p + 1] = hi;
        }
}

// Scan CSZ candidates (one ds_read_b128 each) against both queries' lagged
// thresholds; record keep bits MSB-first: after CSZ shifts, bit (CSZ-1-u)
// holds candidate u. tau is loop-invariant -> all steps independent.
template<int CSZ>
__device__ __forceinline__ void scan_chunk(const float4* __restrict__ seg, int step0,
                                           const float4 p0, const float4 p1,
                                           const float tau0, const float tau1,
                                           unsigned& m0, unsigned& m1)
{
    unsigned a = 0, b = 0;
    #pragma unroll 8
    for (int u = 0; u < CSZ; ++u) {
        const float4 c = seg[step0 + u];
        const float f0 = fmaf(-2.0f, fmaf(p0.x, c.x,
                                          fmaf(p0.y, c.y, p0.z * c.z)), c.w);
        const float f1 = fmaf(-2.0f, fmaf(p1.x, c.x,
                                          fmaf(p1.y, c.y, p1.z * c.z)), c.w);
        a = (a << 1) | (f0 < tau0 ? 1u : 0u);
        b = (b << 1) | (f1 < tau1 ? 1u : 0u);
    }
    m0 = a; m1 = b;
}

// Drain bit-reversed keep masks for both queries. ctz over the reversed mask
// walks candidates in ascending index order (idx = base + bitpos). Exact
// numpy-tree dd recompute, identical to the proven round-3 drain.
__device__ __forceinline__ void drain_pair(unsigned r0, unsigned r1, int base,
                                           const float4 p0, const float4 p1,
                                           float* __restrict__ d0, int* __restrict__ i0,
                                           float* __restrict__ d1, int* __restrict__ i1,
                                           const float4* __restrict__ pts)
{
    while (__any((r0 | r1) != 0)) {
        if (r0) {
            const int bpos = __builtin_ctz(r0);
            r0 &= r0 - 1;
            const int idx = base + bpos;
            const float4 c = pts[swz(idx)];
            const float dot = __fadd_rn(__fadd_rn(__fmul_rn(p0.x, c.x),
                                                  __fmul_rn(p0.y, c.y)),
                                        __fmul_rn(p0.z, c.z));
            const float dd = __fsub_rn(__fadd_rn(p0.w, c.w),
                                       __fmul_rn(2.0f, dot));
            push5(dd, idx, d0, i0);
        }
        if (r1) {
            const int bpos = __builtin_ctz(r1);
            r1 &= r1 - 1;
            const int idx = base + bpos;
            const float4 c = pts[swz(idx)];
            const float dot = __fadd_rn(__fadd_rn(__fmul_rn(p1.x, c.x),
                                                  __fmul_rn(p1.y, c.y)),
                                        __fmul_rn(p1.z, c.z));
            const float dd = __fsub_rn(__fadd_rn(p1.w, c.w),
                                       __fmul_rn(2.0f, dot));
            push5(dd, idx, d1, i1);
        }
    }
}

// Wave-shared lagged threshold: min over the 8 segment-lanes of each query's
// partial 5th-best (subset-5th >= union-5th, so this is >= the global 5th
// and the inflated fast-fma filter can never reject a true top-5 candidate).
__device__ __forceinline__ void share_tau(const float4 p0, const float4 p1,
                                          float d0_4, float d1_4,
                                          float& tau0, float& tau1)
{
    #pragma unroll
    for (int mask = 8; mask < 64; mask <<= 1) {
        d0_4 = fminf(d0_4, __shfl_xor(d0_4, mask));
        d1_4 = fminf(d1_4, __shfl_xor(d1_4, mask));
    }
    tau0 = __fsub_rn(d0_4, p0.w) + 6e-5f;  // inf stays inf
    tau1 = __fsub_rn(d1_4, p1.w) + 6e-5f;
}

__global__ __launch_bounds__(NTHR, 2)
void knn_trace_kernel(const float* __restrict__ pcd, float* __restrict__ trace_out)
{
    __shared__ float4 spts[N_PTS + SEG];   // {x,y,z,|p|^2}, swizzled (65,664 B)

    const int b = blockIdx.y;
    const int t = threadIdx.x;
    const float* __restrict__ batch = pcd + (size_t)b * N_PTS * 3;

    // ---- stage batch into LDS, |p|^2 = (x*x + y*y) + z*z ----
    #pragma unroll
    for (int i = 0; i < N_PTS / NTHR; ++i) {
        const int p = t + i * NTHR;
        const float x = batch[p * 3 + 0];
        const float y = batch[p * 3 + 1];
        const float z = batch[p * 3 + 2];
        const float sq = __fadd_rn(__fadd_rn(__fmul_rn(x, x), __fmul_rn(y, y)),
                                   __fmul_rn(z, z));
        spts[swz(p)] = make_float4(x, y, z, sq);
    }
    __syncthreads();

    const int lane = t & 63;
    const int wave = t >> 6;
    const int j    = lane & 7;             // query slot within octet
    const int s    = lane >> 3;            // segment
    const int qbase = blockIdx.x * QPB + wave * QPW;

    const float4 p0 = spts[swz(qbase + j)];        // octet A query
    const float4 p1 = spts[swz(qbase + 8 + j)];    // octet B query

    float d0[KNN], d1[KNN];
    int   i0[KNN], i1[KNN];
    #pragma unroll
    for (int r = 0; r < KNN; ++r) {
        d0[r] = __builtin_inff(); i0[r] = 0x7fffffff;
        d1[r] = __builtin_inff(); i1[r] = 0x7fffffff;
    }
    float tau0 = __builtin_inff();
    float tau1 = __builtin_inff();

    const float4* __restrict__ seg = spts + (s * SEGLEN + s);  // swz(s*SEGLEN)
    const int idx0 = s * SEGLEN;

    unsigned m0, m1;

    // ---- warm-up: small chunks tighten the shared tau fast ----
    scan_chunk<8>(seg, 0, p0, p1, tau0, tau1, m0, m1);
    drain_pair(__brev(m0), __brev(m1), idx0 + 0 - 24, p0, p1, d0, i0, d1, i1, spts);
    share_tau(p0, p1, d0[KNN - 1], d1[KNN - 1], tau0, tau1);

    scan_chunk<8>(seg, 8, p0, p1, tau0, tau1, m0, m1);
    drain_pair(__brev(m0), __brev(m1), idx0 + 8 - 24, p0, p1, d0, i0, d1, i1, spts);
    share_tau(p0, p1, d0[KNN - 1], d1[KNN - 1], tau0, tau1);

    scan_chunk<16>(seg, 16, p0, p1, tau0, tau1, m0, m1);
    drain_pair(__brev(m0), __brev(m1), idx0 + 16 - 16, p0, p1, d0, i0, d1, i1, spts);
    share_tau(p0, p1, d0[KNN - 1], d1[KNN - 1], tau0, tau1);

    // ---- steady state: 15 chunks of 32 ----
    for (int c = 0; c < 15; ++c) {
        const int s0 = 32 + c * 32;
        scan_chunk<32>(seg, s0, p0, p1, tau0, tau1, m0, m1);
        drain_pair(__brev(m0), __brev(m1), idx0 + s0, p0, p1, d0, i0, d1, i1, spts);
        share_tau(p0, p1, d0[KNN - 1], d1[KNN - 1], tau0, tau1);
    }

    // ---- pack keys = (bits(sqrt(max(dd,0))) << 32) | idx, sort 5 ----
    ull kA[KNN], kB[KNN];
    #pragma unroll
    for (int r = 0; r < KNN; ++r) {
        const float da = __fsqrt_rn(fmaxf(d0[r], 0.0f));
        kA[r] = ((ull)__float_as_uint(da) << 32) | (unsigned)i0[r];
        const float db = __fsqrt_rn(fmaxf(d1[r], 0.0f));
        kB[r] = ((ull)__float_as_uint(db) << 32) | (unsigned)i1[r];
    }
    sort5(kA);
    sort5(kB);

    // ---- butterfly merge across the 8 segment lanes (masks 8,16,32) ----
    #pragma unroll
    for (int mask = 8; mask < 64; mask <<= 1) {
        ull oA[KNN], oB[KNN];
        #pragma unroll
        for (int r = 0; r < KNN; ++r) {
            oA[r] = __shfl_xor(kA[r], mask);
            oB[r] = __shfl_xor(kB[r], mask);
        }
        merge5(kA, oA);
        merge5(kB, oB);
    }

    // ---- epilogue: lane 0..7 -> octet A, lane 8..15 -> octet B ----
    // query id for lane < 16 is exactly qbase + lane.
    if (lane < 16) {
        ull k[KNN];
        #pragma unroll
        for (int r = 0; r < KNN; ++r) k[r] = (lane < 8) ? kA[r] : kB[r];

        float nx[KNN], ny[KNN], nz[KNN];
        #pragma unroll
        for (int r = 0; r < KNN; ++r) {
            const int sel = (int)(k[r] & 0xffffffffull);
            const float4 p = spts[swz(sel)];
            nx[r] = p.x; ny[r] = p.y; nz[r] = p.z;
        }

        float sx = nx[0], sy = ny[0], sz = nz[0];
        #pragma unroll
        for (int r = 1; r < KNN; ++r) {
            sx = __fadd_rn(sx, nx[r]);
            sy = __fadd_rn(sy, ny[r]);
            sz = __fadd_rn(sz, nz[r]);
        }
        const float cx = __fdiv_rn(sx, 5.0f);
        const float cy = __fdiv_rn(sy, 5.0f);
        const float cz = __fdiv_rn(sz, 5.0f);

        float sxx = 0.0f, syy = 0.0f, szz = 0.0f;
        #pragma unroll
        for (int r = 0; r < KNN; ++r) {
            const float dx = __fsub_rn(nx[r], cx);
            const float dy = __fsub_rn(ny[r], cy);
            const float dz = __fsub_rn(nz[r], cz);
            sxx = __fadd_rn(sxx, __fmul_rn(dx, dx));
            syy = __fadd_rn(syy, __fmul_rn(dy, dy));
            szz = __fadd_rn(szz, __fmul_rn(dz, dz));
        }
        const float trace = __fadd_rn(__fadd_rn(__fmul_rn(sxx, 0.25f),
                                                __fmul_rn(syy, 0.25f)),
                                      __fmul_rn(szz, 0.25f));
        trace_out[(size_t)b * N_PTS + qbase + lane] = trace;
    }
}

// Unchanged from rounds 2-3 (passed with absmax 0.0) — keep the reduction
// tree bit-identical.
__global__ __launch_bounds__(256)
void curvature_kernel(const float* __restrict__ trace, float* __restrict__ out)
{
    __shared__ float red[256];
    const int b = blockIdx.x >> 3;
    const int c = blockIdx.x & 7;
    const int t = threadIdx.x;
    const float* __restrict__ tr = trace + (size_t)b * N_PTS;

    float s = 0.0f;
    #pragma unroll
    for (int i = 0; i < N_PTS / 256; ++i)
        s += tr[t + i * 256];
    red[t] = s;
    __syncthreads();
    #pragma unroll
    for (int o = 128; o > 0; o >>= 1) {
        if (t < o) red[t] += red[t + o];
        __syncthreads();
    }
    const float denom = red[0] + 1e-8f;

    float* __restrict__ ob = out + (size_t)b * N_PTS;
    const int x = c * 512 + t;
    ob[x]       = tr[x]       / denom;
    ob[x + 256] = tr[x + 256] / denom;
}

extern "C" void kernel_launch(void* const* d_in, const int* in_sizes, int n_in,
                              void* d_out, int out_size, void* d_ws, size_t ws_size,
                              hipStream_t stream)
{
    (void)in_sizes; (void)n_in; (void)out_size; (void)ws_size;
    const float* pcd = (const float*)d_in[0];   // [8,4096,3] f32
    float* trace = (float*)d_ws;                // [8,4096] f32 scratch
    float* out = (float*)d_out;                 // [8,4096] f32

    dim3 gridA(N_PTS / QPB, BATCH);             // 32 x 8 = 256 blocks (1/CU)
    knn_trace_kernel<<<gridA, NTHR, 0, stream>>>(pcd, trace);
    curvature_kernel<<<BATCH * 8, 256, 0, stream>>>(trace, out);
}